// Round 2
// baseline (431.730 us; speedup 1.0000x reference)
//
#include <hip/hip_runtime.h>
#include <hip/hip_bf16.h>

typedef float f32x4 __attribute__((ext_vector_type(4)));
typedef __bf16 bf16x8 __attribute__((ext_vector_type(8)));
typedef unsigned short u16x8 __attribute__((ext_vector_type(8)));
typedef unsigned short u16x4 __attribute__((ext_vector_type(4)));

__device__ __forceinline__ unsigned short f2bf(float f) {
  union { float f; unsigned int u; } v; v.f = f;
  return (unsigned short)((v.u + 0x7FFFu + ((v.u >> 16) & 1u)) >> 16);
}

__device__ __forceinline__ f32x4 mfma16(bf16x8 a, bf16x8 b, f32x4 c) {
  return __builtin_amdgcn_mfma_f32_16x16x32_bf16(a, b, c, 0, 0, 0);
}

// ---------------- small utility kernels ----------------

__global__ void concat_bias_k(const float* __restrict__ qb, const float* __restrict__ kb,
                              const float* __restrict__ vb, float* __restrict__ out) {
  const int i = blockIdx.x * 256 + threadIdx.x;
  if (i >= 3072) return;
  const float* s = (i < 1024) ? qb : (i < 2048 ? kb : vb);
  out[i] = s[i & 1023];
}

// fp32 [R,C] -> bf16 [C,R]
__global__ void tcvt_k(const float* __restrict__ in, unsigned short* __restrict__ out,
                       int R, int C) {
  __shared__ float tile[32][33];
  const int x = blockIdx.x * 32 + threadIdx.x;
  const int y0 = blockIdx.y * 32;
#pragma unroll
  for (int i = 0; i < 32; i += 8)
    tile[threadIdx.y + i][threadIdx.x] = in[(size_t)(y0 + threadIdx.y + i) * C + x];
  __syncthreads();
  const int ox = y0 + threadIdx.x;
  const int oy0 = blockIdx.x * 32;
#pragma unroll
  for (int i = 0; i < 32; i += 8)
    out[(size_t)(oy0 + threadIdx.y + i) * R + ox] = f2bf(tile[threadIdx.x][threadIdx.y + i]);
}

__global__ void cvt_k(const float* __restrict__ in, unsigned short* __restrict__ out, int n) {
  const int i = (blockIdx.x * 256 + threadIdx.x) * 4;
  if (i >= n) return;
  const f32x4 v = *(const f32x4*)(in + i);
  u16x4 o;
#pragma unroll
  for (int k = 0; k < 4; ++k) o[k] = f2bf(v[k]);
  *(u16x4*)(out + i) = o;
}

// Wqkv^T[(m*1024 + h*64 + e)*1024 + d] = sum_r U_m[d,h,r] * V_m[h,r,e]
__global__ __launch_bounds__(256) void wqkv_pre_k(
    const float* __restrict__ qU, const float* __restrict__ qV,
    const float* __restrict__ kU, const float* __restrict__ kV,
    const float* __restrict__ vU, const float* __restrict__ vV,
    unsigned short* __restrict__ WT) {
  __shared__ float Us[64][48];
  __shared__ float Vs[48][64];
  const int m = blockIdx.y >> 4, h = blockIdx.y & 15;
  const int d0 = blockIdx.x * 64;
  const float* U = (m == 0) ? qU : (m == 1 ? kU : vU);
  const float* V = (m == 0) ? qV : (m == 1 ? kV : vV);
  const int t = threadIdx.x;
  for (int idx = t; idx < 64 * 48; idx += 256) {
    const int d = idx / 48, r = idx - d * 48;
    Us[d][r] = U[(size_t)(d0 + d) * 768 + h * 48 + r];
  }
  for (int idx = t; idx < 48 * 64; idx += 256) {
    const int r = idx >> 6, e = idx & 63;
    Vs[r][e] = V[(h * 48 + r) * 64 + e];
  }
  __syncthreads();
  const int e = t & 63, dg = t >> 6;
  for (int j = 0; j < 16; ++j) {
    const int d = dg * 16 + j;
    float s = 0.f;
#pragma unroll
    for (int r = 0; r < 48; ++r) s = fmaf(Us[d][r], Vs[r][e], s);
    WT[(size_t)(m * 1024 + h * 64 + e) * 1024 + d0 + d] = f2bf(s);
  }
}

// LayerNorm over D=1024, fp32 in, bf16 out. One block per row.
__global__ __launch_bounds__(256) void ln_k(
    const float* __restrict__ in, const float* __restrict__ gw,
    const float* __restrict__ bw, unsigned short* __restrict__ out) {
  const int row = blockIdx.x, t = threadIdx.x;
  const f32x4 v = *(const f32x4*)(in + (size_t)row * 1024 + t * 4);
  float s = v[0] + v[1] + v[2] + v[3];
  float ss = v[0] * v[0] + v[1] * v[1] + v[2] * v[2] + v[3] * v[3];
#pragma unroll
  for (int off = 1; off < 64; off <<= 1) {
    s += __shfl_xor(s, off);
    ss += __shfl_xor(ss, off);
  }
  __shared__ float red[8];
  if ((t & 63) == 0) { red[(t >> 6) * 2] = s; red[(t >> 6) * 2 + 1] = ss; }
  __syncthreads();
  s = red[0] + red[2] + red[4] + red[6];
  ss = red[1] + red[3] + red[5] + red[7];
  const float mean = s * (1.0f / 1024.0f);
  const float rstd = rsqrtf(ss * (1.0f / 1024.0f) - mean * mean + 1e-5f);
  const f32x4 g4 = *(const f32x4*)(gw + t * 4);
  const f32x4 b4 = *(const f32x4*)(bw + t * 4);
  u16x4 o;
#pragma unroll
  for (int i = 0; i < 4; ++i) o[i] = f2bf((v[i] - mean) * rstd * g4[i] + b4[i]);
  *(u16x4*)(out + (size_t)row * 1024 + t * 4) = o;
}

// ---------------- generic bf16 MFMA GEMM ----------------
// C[M,N] = A[M,K] @ B[K,N], with B supplied transposed: Bt[N,K]. Both bf16,
// row-major along K. BM=128 fixed, BN in {64,128}. 256 threads = 4 waves (2x2),
// wave tile 64 x BN/2, 16x16x32 MFMA frags.
// Staging: thread t loads 16 elems (two u16x8) of row t>>1, cols (t&1)*16..+15.
// EPI: 0=none, 1=+bias, 2=+bias+gelu(tanh), 3=+bias+residual. OUTBF: bf16/f32 out.
template <int BN, int EPI, int OUTBF>
__global__ __launch_bounds__(256) void gemm_k(
    const unsigned short* __restrict__ A, const unsigned short* __restrict__ Bt,
    const float* __restrict__ bias, const float* __restrict__ resid,
    void* __restrict__ Cout, int M, int N, int K) {
  constexpr int FN = BN / 32;
  __shared__ unsigned short As[128][40];  // +8 pad: 80B row stride, 2-way banks, 16B aligned
  __shared__ unsigned short Bs[BN][40];
  const int t = threadIdx.x;
  const int lane = t & 63, wid = t >> 6;
  const int m0 = blockIdx.y * 128, n0 = blockIdx.x * BN;
  const int wm = (wid >> 1) * 64, wn = (wid & 1) * (BN / 2);
  const int fr = lane & 15, fg = (lane >> 4) * 8;

  f32x4 acc[4][FN];
#pragma unroll
  for (int i = 0; i < 4; ++i)
#pragma unroll
    for (int j = 0; j < FN; ++j) acc[i][j] = (f32x4){0.f, 0.f, 0.f, 0.f};

  const int arow = t >> 1, akc = (t & 1) * 16;
  const unsigned short* Ap = A + (size_t)(m0 + arow) * K + akc;
  const bool bact = (t < 2 * BN);
  const int brow = arow & (BN - 1);
  const unsigned short* Bp = Bt + (size_t)(n0 + brow) * K + akc;

  for (int kt = 0; kt < K; kt += 32) {
    const u16x8 av0 = *(const u16x8*)Ap;
    const u16x8 av1 = *(const u16x8*)(Ap + 8);
    u16x8 bv0 = {}, bv1 = {};
    if (bact) { bv0 = *(const u16x8*)Bp; bv1 = *(const u16x8*)(Bp + 8); }
    __syncthreads();
    *(u16x8*)&As[arow][akc] = av0;
    *(u16x8*)&As[arow][akc + 8] = av1;
    if (bact) {
      *(u16x8*)&Bs[brow][akc] = bv0;
      *(u16x8*)&Bs[brow][akc + 8] = bv1;
    }
    __syncthreads();
    bf16x8 af[4], bfr[FN];
#pragma unroll
    for (int i = 0; i < 4; ++i) af[i] = *(const bf16x8*)&As[wm + i * 16 + fr][fg];
#pragma unroll
    for (int j = 0; j < FN; ++j) bfr[j] = *(const bf16x8*)&Bs[wn + j * 16 + fr][fg];
#pragma unroll
    for (int i = 0; i < 4; ++i)
#pragma unroll
      for (int j = 0; j < FN; ++j) acc[i][j] = mfma16(af[i], bfr[j], acc[i][j]);
    Ap += 32;
    Bp += 32;
  }

#pragma unroll
  for (int j = 0; j < FN; ++j) {
    const int col = n0 + wn + j * 16 + fr;
    const float bval = (EPI >= 1) ? bias[col] : 0.0f;
#pragma unroll
    for (int i = 0; i < 4; ++i) {
#pragma unroll
      for (int r = 0; r < 4; ++r) {
        const int row = m0 + wm + i * 16 + ((lane >> 4) << 2) + r;
        float v = acc[i][j][r] + bval;
        if (EPI == 2) {  // gelu tanh-approx: v * sigmoid(2z)
          const float z = 0.7978845608028654f * (v + 0.044715f * v * v * v);
          v = v - v / (__expf(2.0f * z) + 1.0f);
        }
        if (EPI == 3) v += resid[(size_t)row * N + col];
        if (OUTBF)
          ((unsigned short*)Cout)[(size_t)row * N + col] = f2bf(v);
        else
          ((float*)Cout)[(size_t)row * N + col] = v;
      }
    }
  }
}

// ---------------- causal flash attention ----------------
// QKV bf16 [B*S, 3072], cols: Q = h*64+e, K = 1024+h*64+e, V = 2048+h*64+e.
// grid (S/64, B*H), 256 threads = 4 waves; wave w owns q rows tile*64+16w..+15.
__global__ __launch_bounds__(256) void attn_k(
    const unsigned short* __restrict__ QKV, unsigned short* __restrict__ ctx) {
  __shared__ unsigned short Ks[64][72];      // [key][dh]
  __shared__ unsigned short Vt[64][72];      // [dh][key]
  __shared__ unsigned short Ps[4][16][72];   // per-wave P [qrow][key]
  const int qt = blockIdx.x, bh = blockIdx.y;
  const int b = bh >> 4, h = bh & 15;
  const int t = threadIdx.x, lane = t & 63, w = t >> 6;
  const int g = lane >> 4, c = lane & 15;
  const int q0 = qt * 64;
  const size_t base = (size_t)b * 2048 * 3072;

  bf16x8 qf0, qf1;
  {
    const unsigned short* qp = QKV + base + (size_t)(q0 + w * 16 + c) * 3072 + h * 64 + g * 8;
    qf0 = *(const bf16x8*)qp;
    qf1 = *(const bf16x8*)(qp + 32);
  }

  f32x4 o[4];
#pragma unroll
  for (int d = 0; d < 4; ++d) o[d] = (f32x4){0.f, 0.f, 0.f, 0.f};
  float mrow[4], lrow[4];
#pragma unroll
  for (int r = 0; r < 4; ++r) { mrow[r] = -1e30f; lrow[r] = 0.f; }

  const int sr = t >> 2, sc = (t & 3) * 16;
  const unsigned short* Kg = QKV + base + (size_t)sr * 3072 + 1024 + h * 64 + sc;
  const unsigned short* Vg = QKV + base + (size_t)sr * 3072 + 2048 + h * 64 + sc;

  for (int kt = 0; kt <= qt; ++kt) {
    const size_t koff = (size_t)kt * 64 * 3072;
    const u16x8 k0 = *(const u16x8*)(Kg + koff);
    const u16x8 k1 = *(const u16x8*)(Kg + koff + 8);
    const u16x8 v0 = *(const u16x8*)(Vg + koff);
    const u16x8 v1 = *(const u16x8*)(Vg + koff + 8);
    __syncthreads();
    *(u16x8*)&Ks[sr][sc] = k0;
    *(u16x8*)&Ks[sr][sc + 8] = k1;
#pragma unroll
    for (int i = 0; i < 8; ++i) Vt[sc + i][sr] = v0[i];
#pragma unroll
    for (int i = 0; i < 8; ++i) Vt[sc + 8 + i][sr] = v1[i];
    __syncthreads();

    // S = Q K^T * scale  (C layout: col=key=c, row=q=(4g+r))
    f32x4 s4[4];
#pragma unroll
    for (int t16 = 0; t16 < 4; ++t16) {
      f32x4 a = (f32x4){0.f, 0.f, 0.f, 0.f};
      a = mfma16(qf0, *(const bf16x8*)&Ks[t16 * 16 + c][g * 8], a);
      a = mfma16(qf1, *(const bf16x8*)&Ks[t16 * 16 + c][32 + g * 8], a);
#pragma unroll
      for (int r = 0; r < 4; ++r) s4[t16][r] = a[r] * 0.125f;
    }
    if (kt == qt) {  // diagonal tile: causal mask
      const int qbase = q0 + w * 16 + g * 4;
      const int kbase = kt * 64 + c;
#pragma unroll
      for (int t16 = 0; t16 < 4; ++t16)
#pragma unroll
        for (int r = 0; r < 4; ++r)
          if (kbase + t16 * 16 > qbase + r) s4[t16][r] = -1e30f;
    }
    // online softmax: row reduce across 16 key-lanes
    float mx[4];
#pragma unroll
    for (int r = 0; r < 4; ++r)
      mx[r] = fmaxf(fmaxf(s4[0][r], s4[1][r]), fmaxf(s4[2][r], s4[3][r]));
#pragma unroll
    for (int off = 1; off < 16; off <<= 1)
#pragma unroll
      for (int r = 0; r < 4; ++r) mx[r] = fmaxf(mx[r], __shfl_xor(mx[r], off));
    float fac[4];
#pragma unroll
    for (int r = 0; r < 4; ++r) {
      const float mn = fmaxf(mrow[r], mx[r]);
      fac[r] = __expf(mrow[r] - mn);
      mrow[r] = mn;
    }
    float psum[4] = {0.f, 0.f, 0.f, 0.f};
#pragma unroll
    for (int t16 = 0; t16 < 4; ++t16)
#pragma unroll
      for (int r = 0; r < 4; ++r) {
        const float pv = __expf(s4[t16][r] - mrow[r]);
        psum[r] += pv;
        Ps[w][g * 4 + r][t16 * 16 + c] = f2bf(pv);
      }
#pragma unroll
    for (int off = 1; off < 16; off <<= 1)
#pragma unroll
      for (int r = 0; r < 4; ++r) psum[r] += __shfl_xor(psum[r], off);
#pragma unroll
    for (int r = 0; r < 4; ++r) lrow[r] = lrow[r] * fac[r] + psum[r];
#pragma unroll
    for (int d = 0; d < 4; ++d)
#pragma unroll
      for (int r = 0; r < 4; ++r) o[d][r] *= fac[r];
    // O += P V   (A-frag from Ps, B-frag contiguous from Vt)
#pragma unroll
    for (int ks = 0; ks < 2; ++ks) {
      const bf16x8 pf = *(const bf16x8*)&Ps[w][c][ks * 32 + g * 8];
#pragma unroll
      for (int d = 0; d < 4; ++d) {
        const bf16x8 vf = *(const bf16x8*)&Vt[d * 16 + c][ks * 32 + g * 8];
        o[d] = mfma16(pf, vf, o[d]);
      }
    }
  }
#pragma unroll
  for (int d = 0; d < 4; ++d)
#pragma unroll
    for (int r = 0; r < 4; ++r) {
      const float v = o[d][r] / lrow[r];
      ctx[(size_t)(b * 2048 + q0 + w * 16 + g * 4 + r) * 1024 + h * 64 + d * 16 + c] = f2bf(v);
    }
}

// ---------------- launch ----------------

extern "C" void kernel_launch(void* const* d_in, const int* in_sizes, int n_in,
                              void* d_out, int out_size, void* d_ws, size_t ws_size,
                              hipStream_t stream) {
  const float* hidden = (const float*)d_in[0];
  const float* ln1g = (const float*)d_in[1];
  const float* ln1b = (const float*)d_in[2];
  const float* ln2g = (const float*)d_in[3];
  const float* ln2b = (const float*)d_in[4];
  const float* qU = (const float*)d_in[5];
  const float* qV = (const float*)d_in[6];
  const float* qb = (const float*)d_in[7];
  const float* kU = (const float*)d_in[8];
  const float* kV = (const float*)d_in[9];
  const float* kb = (const float*)d_in[10];
  const float* vU = (const float*)d_in[11];
  const float* vV = (const float*)d_in[12];
  const float* vb = (const float*)d_in[13];
  const float* outU = (const float*)d_in[14];
  const float* outV = (const float*)d_in[15];
  const float* outb = (const float*)d_in[16];
  const float* fc1U = (const float*)d_in[17];
  const float* fc1V = (const float*)d_in[18];
  const float* fc1b = (const float*)d_in[19];
  const float* fc2U = (const float*)d_in[20];
  const float* fc2V = (const float*)d_in[21];
  const float* fc2b = (const float*)d_in[22];
  float* out = (float*)d_out;

  // workspace carve (~81 MB), with lifetime-based aliasing
  char* p = (char*)d_ws;
  unsigned short* x1x2 = (unsigned short*)p; p += (size_t)4096 * 1024 * 2;   // x1 (LN1), later x2 (LN2)
  unsigned short* WqT_t1 = (unsigned short*)p; p += (size_t)3072 * 1024 * 2; // Wqkv^T, later t1
  float* bqkv = (float*)p; p += 3072 * 4;
  char* bigA = p; p += (size_t)4096 * 3072 * 2 + (size_t)4096 * 1024 * 2;    // QKV + ctx, later hmid
  unsigned short* QKV = (unsigned short*)bigA;
  unsigned short* ctxb = (unsigned short*)(bigA + (size_t)4096 * 3072 * 2);
  unsigned short* hmid = (unsigned short*)bigA;
  char* wo = p; p += (size_t)1024 * 768 * 2 * 2 + (size_t)1024 * 1024 * 2;   // outU,outV^T,Wout^T, later t2
  unsigned short* outUb = (unsigned short*)wo;
  unsigned short* outVT = (unsigned short*)(wo + (size_t)1024 * 768 * 2);
  unsigned short* WoutT = (unsigned short*)(wo + (size_t)1024 * 768 * 2 * 2);
  unsigned short* t2 = (unsigned short*)wo;
  float* hbuf = (float*)p; p += (size_t)4096 * 1024 * 4;                     // h (fp32 residual)
  unsigned short* fc1UT = (unsigned short*)p; p += (size_t)512 * 1024 * 2;
  unsigned short* fc1VT = (unsigned short*)p; p += (size_t)4096 * 512 * 2;
  unsigned short* fc2UT = (unsigned short*)p; p += (size_t)512 * 4096 * 2;
  unsigned short* fc2VT = (unsigned short*)p; p += (size_t)1024 * 512 * 2;

  const dim3 b256(256);
  const dim3 tb(32, 8);

  // weight prep
  concat_bias_k<<<12, b256, 0, stream>>>(qb, kb, vb, bqkv);
  wqkv_pre_k<<<dim3(16, 48), b256, 0, stream>>>(qU, qV, kU, kV, vU, vV, WqT_t1);
  tcvt_k<<<dim3(32, 24), tb, 0, stream>>>(outV, outVT, 768, 1024);
  cvt_k<<<768, b256, 0, stream>>>(outU, outUb, 1024 * 768);
  tcvt_k<<<dim3(16, 32), tb, 0, stream>>>(fc1U, fc1UT, 1024, 512);
  tcvt_k<<<dim3(128, 16), tb, 0, stream>>>(fc1V, fc1VT, 512, 4096);
  tcvt_k<<<dim3(16, 128), tb, 0, stream>>>(fc2U, fc2UT, 4096, 512);
  tcvt_k<<<dim3(32, 16), tb, 0, stream>>>(fc2V, fc2VT, 512, 1024);

  // attention path
  ln_k<<<4096, b256, 0, stream>>>(hidden, ln1g, ln1b, x1x2);
  gemm_k<128, 1, 1><<<dim3(24, 32), b256, 0, stream>>>(x1x2, WqT_t1, bqkv, nullptr, QKV, 4096, 3072, 1024);
  gemm_k<128, 0, 1><<<dim3(8, 8), b256, 0, stream>>>(outVT, outUb, nullptr, nullptr, WoutT, 1024, 1024, 768);
  attn_k<<<dim3(32, 32), b256, 0, stream>>>(QKV, ctxb);
  gemm_k<128, 3, 0><<<dim3(8, 32), b256, 0, stream>>>(ctxb, WoutT, outb, hidden, hbuf, 4096, 1024, 1024);

  // MLP path
  ln_k<<<4096, b256, 0, stream>>>(hbuf, ln2g, ln2b, x1x2);
  gemm_k<64, 0, 1><<<dim3(8, 32), b256, 0, stream>>>(x1x2, fc1UT, nullptr, nullptr, WqT_t1, 4096, 512, 1024);
  gemm_k<128, 2, 1><<<dim3(32, 32), b256, 0, stream>>>(WqT_t1, fc1VT, fc1b, nullptr, hmid, 4096, 4096, 512);
  gemm_k<64, 0, 1><<<dim3(8, 32), b256, 0, stream>>>(hmid, fc2UT, nullptr, nullptr, t2, 4096, 512, 4096);
  gemm_k<128, 3, 0><<<dim3(8, 32), b256, 0, stream>>>(t2, fc2VT, fc2b, hbuf, out, 4096, 1024, 512);
}

// Round 3
// 348.214 us; speedup vs baseline: 1.2398x; 1.2398x over previous
//
#include <hip/hip_runtime.h>
#include <hip/hip_bf16.h>

typedef float f32x4 __attribute__((ext_vector_type(4)));
typedef __bf16 bf16x8 __attribute__((ext_vector_type(8)));
typedef unsigned short u16x8 __attribute__((ext_vector_type(8)));
typedef unsigned short u16x4 __attribute__((ext_vector_type(4)));

__device__ __forceinline__ unsigned short f2bf(float f) {
  union { float f; unsigned int u; } v; v.f = f;
  return (unsigned short)((v.u + 0x7FFFu + ((v.u >> 16) & 1u)) >> 16);
}

__device__ __forceinline__ f32x4 mfma16(bf16x8 a, bf16x8 b, f32x4 c) {
  return __builtin_amdgcn_mfma_f32_16x16x32_bf16(a, b, c, 0, 0, 0);
}

__device__ __forceinline__ void gload16(const unsigned short* g, unsigned short* l) {
  __builtin_amdgcn_global_load_lds(
      (const __attribute__((address_space(1))) void*)g,
      (__attribute__((address_space(3))) void*)l, 16, 0, 0);
}

// ---------------- small utility kernels ----------------

__global__ void concat_bias_k(const float* __restrict__ qb, const float* __restrict__ kb,
                              const float* __restrict__ vb, float* __restrict__ out) {
  const int i = blockIdx.x * 256 + threadIdx.x;
  if (i >= 3072) return;
  const float* s = (i < 1024) ? qb : (i < 2048 ? kb : vb);
  out[i] = s[i & 1023];
}

// fp32 [R,C] -> bf16 [C,R]
__global__ void tcvt_k(const float* __restrict__ in, unsigned short* __restrict__ out,
                       int R, int C) {
  __shared__ float tile[32][33];
  const int x = blockIdx.x * 32 + threadIdx.x;
  const int y0 = blockIdx.y * 32;
#pragma unroll
  for (int i = 0; i < 32; i += 8)
    tile[threadIdx.y + i][threadIdx.x] = in[(size_t)(y0 + threadIdx.y + i) * C + x];
  __syncthreads();
  const int ox = y0 + threadIdx.x;
  const int oy0 = blockIdx.x * 32;
#pragma unroll
  for (int i = 0; i < 32; i += 8)
    out[(size_t)(oy0 + threadIdx.y + i) * R + ox] = f2bf(tile[threadIdx.x][threadIdx.y + i]);
}

__global__ void cvt_k(const float* __restrict__ in, unsigned short* __restrict__ out, int n) {
  const int i = (blockIdx.x * 256 + threadIdx.x) * 4;
  if (i >= n) return;
  const f32x4 v = *(const f32x4*)(in + i);
  u16x4 o;
#pragma unroll
  for (int k = 0; k < 4; ++k) o[k] = f2bf(v[k]);
  *(u16x4*)(out + i) = o;
}

// V-transpose: QKV[b][s][2048 + h*64 + d] -> VT[(b*16+h)][d][s]  (bf16)
__global__ void vtr_k(const unsigned short* __restrict__ QKV, unsigned short* __restrict__ VT) {
  __shared__ unsigned short tile[32][33];
  const int bh = blockIdx.z, b = bh >> 4, h = bh & 15;
  const int s0 = blockIdx.x * 32, d0 = blockIdx.y * 32;
  const unsigned short* src = QKV + (size_t)b * 2048 * 3072 + 2048 + h * 64;
#pragma unroll
  for (int i = 0; i < 32; i += 8)
    tile[threadIdx.y + i][threadIdx.x] = src[(size_t)(s0 + threadIdx.y + i) * 3072 + d0 + threadIdx.x];
  __syncthreads();
  unsigned short* dst = VT + (size_t)bh * 64 * 2048;
#pragma unroll
  for (int i = 0; i < 32; i += 8)
    dst[(size_t)(d0 + threadIdx.y + i) * 2048 + s0 + threadIdx.x] = tile[threadIdx.x][threadIdx.y + i];
}

// Wqkv^T[(m*1024 + h*64 + e)*1024 + d] = sum_r U_m[d,h,r] * V_m[h,r,e]
__global__ __launch_bounds__(256) void wqkv_pre_k(
    const float* __restrict__ qU, const float* __restrict__ qV,
    const float* __restrict__ kU, const float* __restrict__ kV,
    const float* __restrict__ vU, const float* __restrict__ vV,
    unsigned short* __restrict__ WT) {
  __shared__ float Us[64][48];
  __shared__ float Vs[48][64];
  const int m = blockIdx.y >> 4, h = blockIdx.y & 15;
  const int d0 = blockIdx.x * 64;
  const float* U = (m == 0) ? qU : (m == 1 ? kU : vU);
  const float* V = (m == 0) ? qV : (m == 1 ? kV : vV);
  const int t = threadIdx.x;
  for (int idx = t; idx < 64 * 48; idx += 256) {
    const int d = idx / 48, r = idx - d * 48;
    Us[d][r] = U[(size_t)(d0 + d) * 768 + h * 48 + r];
  }
  for (int idx = t; idx < 48 * 64; idx += 256) {
    const int r = idx >> 6, e = idx & 63;
    Vs[r][e] = V[(h * 48 + r) * 64 + e];
  }
  __syncthreads();
  const int e = t & 63, dg = t >> 6;
  for (int j = 0; j < 16; ++j) {
    const int d = dg * 16 + j;
    float s = 0.f;
#pragma unroll
    for (int r = 0; r < 48; ++r) s = fmaf(Us[d][r], Vs[r][e], s);
    WT[(size_t)(m * 1024 + h * 64 + e) * 1024 + d0 + d] = f2bf(s);
  }
}

// LayerNorm over D=1024, fp32 in, bf16 out. One block per row.
__global__ __launch_bounds__(256) void ln_k(
    const float* __restrict__ in, const float* __restrict__ gw,
    const float* __restrict__ bw, unsigned short* __restrict__ out) {
  const int row = blockIdx.x, t = threadIdx.x;
  const f32x4 v = *(const f32x4*)(in + (size_t)row * 1024 + t * 4);
  float s = v[0] + v[1] + v[2] + v[3];
  float ss = v[0] * v[0] + v[1] * v[1] + v[2] * v[2] + v[3] * v[3];
#pragma unroll
  for (int off = 1; off < 64; off <<= 1) {
    s += __shfl_xor(s, off);
    ss += __shfl_xor(ss, off);
  }
  __shared__ float red[8];
  if ((t & 63) == 0) { red[(t >> 6) * 2] = s; red[(t >> 6) * 2 + 1] = ss; }
  __syncthreads();
  s = red[0] + red[2] + red[4] + red[6];
  ss = red[1] + red[3] + red[5] + red[7];
  const float mean = s * (1.0f / 1024.0f);
  const float rstd = rsqrtf(ss * (1.0f / 1024.0f) - mean * mean + 1e-5f);
  const f32x4 g4 = *(const f32x4*)(gw + t * 4);
  const f32x4 b4 = *(const f32x4*)(bw + t * 4);
  u16x4 o;
#pragma unroll
  for (int i = 0; i < 4; ++i) o[i] = f2bf((v[i] - mean) * rstd * g4[i] + b4[i]);
  *(u16x4*)(out + (size_t)row * 1024 + t * 4) = o;
}

// ---------------- generic bf16 MFMA GEMM (global_load_lds staging) ----------------
// C[M,N] = A[M,K] @ Bt[N,K]^T, bf16 in, fp32 acc. BM=128, BN in {64,128},
// 256 threads = 4 waves (2x2), 16x16x32 MFMA. LDS linear [rows][32], 64B row
// stride -> frag ds_read_b128 at natural 8cy, no padding needed.
// EPI: 0=none, 1=+bias, 2=+bias+gelu(tanh), 3=+bias+residual. OUTBF: bf16/f32 out.
template <int BN, int EPI, int OUTBF>
__global__ __launch_bounds__(256) void gemm_k(
    const unsigned short* __restrict__ A, const unsigned short* __restrict__ Bt,
    const float* __restrict__ bias, const float* __restrict__ resid,
    void* __restrict__ Cout, int M, int N, int K) {
  constexpr int FN = BN / 32;
  __shared__ unsigned short As[128 * 32];
  __shared__ unsigned short Bs[BN * 32];
  const int t = threadIdx.x;
  const int lane = t & 63, wid = t >> 6;
  const int m0 = blockIdx.y * 128, n0 = blockIdx.x * BN;
  const int wm = (wid >> 1) * 64, wn = (wid & 1) * (BN / 2);
  const int fr = lane & 15, fg = (lane >> 4) * 8;

  f32x4 acc[4][FN];
#pragma unroll
  for (int i = 0; i < 4; ++i)
#pragma unroll
    for (int j = 0; j < FN; ++j) acc[i][j] = (f32x4){0.f, 0.f, 0.f, 0.f};

  // staging: chunk = 1 KiB = 16 rows x 32 cols; lane l covers row l>>2, col8 (l&3)*8
  const int sub = lane >> 2, c8 = (lane & 3) * 8;
  const unsigned short* Ag0 = A + (size_t)(m0 + wid * 16 + sub) * K + c8;
  const unsigned short* Ag1 = A + (size_t)(m0 + (wid + 4) * 16 + sub) * K + c8;
  unsigned short* Al0 = &As[wid * 512];
  unsigned short* Al1 = &As[(wid + 4) * 512];
  const unsigned short* Bg0 = Bt + (size_t)(n0 + wid * 16 + sub) * K + c8;
  unsigned short* Bl0 = &Bs[wid * 512];
  const unsigned short* Bg1 = (BN == 128) ? Bt + (size_t)(n0 + (wid + 4) * 16 + sub) * K + c8 : nullptr;
  unsigned short* Bl1 = (BN == 128) ? &Bs[(wid + 4) * 512] : nullptr;

  for (int kt = 0; kt < K; kt += 32) {
    __syncthreads();
    gload16(Ag0 + kt, Al0);
    gload16(Ag1 + kt, Al1);
    gload16(Bg0 + kt, Bl0);
    if (BN == 128) gload16(Bg1 + kt, Bl1);
    __syncthreads();  // drains vmcnt -> LDS tile ready
    bf16x8 af[4], bfr[FN];
#pragma unroll
    for (int i = 0; i < 4; ++i) af[i] = *(const bf16x8*)&As[(wm + i * 16 + fr) * 32 + fg];
#pragma unroll
    for (int j = 0; j < FN; ++j) bfr[j] = *(const bf16x8*)&Bs[(wn + j * 16 + fr) * 32 + fg];
#pragma unroll
    for (int i = 0; i < 4; ++i)
#pragma unroll
      for (int j = 0; j < FN; ++j) acc[i][j] = mfma16(af[i], bfr[j], acc[i][j]);
  }

#pragma unroll
  for (int j = 0; j < FN; ++j) {
    const int col = n0 + wn + j * 16 + fr;
    const float bval = (EPI >= 1) ? bias[col] : 0.0f;
#pragma unroll
    for (int i = 0; i < 4; ++i) {
#pragma unroll
      for (int r = 0; r < 4; ++r) {
        const int row = m0 + wm + i * 16 + ((lane >> 4) << 2) + r;
        float v = acc[i][j][r] + bval;
        if (EPI == 2) {  // gelu tanh-approx: v * sigmoid(2z)
          const float z = 0.7978845608028654f * (v + 0.044715f * v * v * v);
          v = v - v / (__expf(2.0f * z) + 1.0f);
        }
        if (EPI == 3) v += resid[(size_t)row * N + col];
        if (OUTBF)
          ((unsigned short*)Cout)[(size_t)row * N + col] = f2bf(v);
        else
          ((float*)Cout)[(size_t)row * N + col] = v;
      }
    }
  }
}

// ---------------- causal flash attention ----------------
// QKV bf16 [B*S,3072] (Q: h*64+e, K: 1024+h*64+e), V pre-transposed VT[bh][dh][S].
// grid (16, 32): block p handles q-tiles {p, 31-p} (uniform 33 kv-iters), bh = y.
// 256 threads = 4 waves; wave w owns q rows qt*64 + 16w .. +15.
__global__ __launch_bounds__(256) void attn_k(
    const unsigned short* __restrict__ QKV, const unsigned short* __restrict__ VT,
    unsigned short* __restrict__ ctx) {
  __shared__ unsigned short Ks[64][72];      // [key][dh]
  __shared__ unsigned short Vs[64][72];      // [dh][key]
  __shared__ unsigned short Ps[4][16][72];   // per-wave P [qrow][key]
  const int p = blockIdx.x, bh = blockIdx.y;
  const int b = bh >> 4, h = bh & 15;
  const int t = threadIdx.x, lane = t & 63, w = t >> 6;
  const int g = lane >> 4, c = lane & 15;
  const size_t base = (size_t)b * 2048 * 3072;

  const int sr = t >> 2, sc = (t & 3) * 16;
  const unsigned short* Kg = QKV + base + (size_t)sr * 3072 + 1024 + h * 64 + sc;
  const unsigned short* Vg = VT + ((size_t)bh * 64 + sr) * 2048 + sc;

  for (int ph = 0; ph < 2; ++ph) {
    const int qt = ph ? (31 - p) : p;
    const int q0 = qt * 64;

    const unsigned short* qp = QKV + base + (size_t)(q0 + w * 16 + c) * 3072 + h * 64 + g * 8;
    const bf16x8 qf0 = *(const bf16x8*)qp;
    const bf16x8 qf1 = *(const bf16x8*)(qp + 32);

    f32x4 o[4];
#pragma unroll
    for (int d = 0; d < 4; ++d) o[d] = (f32x4){0.f, 0.f, 0.f, 0.f};
    float mrow[4], lrow[4];
#pragma unroll
    for (int r = 0; r < 4; ++r) { mrow[r] = -1e30f; lrow[r] = 0.f; }

    // prologue: tile 0 into regs
    u16x8 kr0 = *(const u16x8*)(Kg);
    u16x8 kr1 = *(const u16x8*)(Kg + 8);
    u16x8 vr0 = *(const u16x8*)(Vg);
    u16x8 vr1 = *(const u16x8*)(Vg + 8);

    for (int kt = 0; kt <= qt; ++kt) {
      __syncthreads();  // prev iter LDS reads done (and prefetch arrived)
      *(u16x8*)&Ks[sr][sc] = kr0;
      *(u16x8*)&Ks[sr][sc + 8] = kr1;
      *(u16x8*)&Vs[sr][sc] = vr0;
      *(u16x8*)&Vs[sr][sc + 8] = vr1;
      __syncthreads();
      if (kt < qt) {  // prefetch next tile; in flight across the compute below
        const size_t ko = (size_t)(kt + 1) * 64 * 3072;
        kr0 = *(const u16x8*)(Kg + ko);
        kr1 = *(const u16x8*)(Kg + ko + 8);
        const int vo = (kt + 1) * 64;
        vr0 = *(const u16x8*)(Vg + vo);
        vr1 = *(const u16x8*)(Vg + vo + 8);
      }

      // S = Q K^T * scale  (C layout: col=key=c, row=q=4g+r)
      f32x4 s4[4];
#pragma unroll
      for (int t16 = 0; t16 < 4; ++t16) {
        f32x4 a = (f32x4){0.f, 0.f, 0.f, 0.f};
        a = mfma16(qf0, *(const bf16x8*)&Ks[t16 * 16 + c][g * 8], a);
        a = mfma16(qf1, *(const bf16x8*)&Ks[t16 * 16 + c][32 + g * 8], a);
#pragma unroll
        for (int r = 0; r < 4; ++r) s4[t16][r] = a[r] * 0.125f;
      }
      if (kt == qt) {  // diagonal tile: causal mask
        const int qbase = q0 + w * 16 + g * 4;
        const int kbase = kt * 64 + c;
#pragma unroll
        for (int t16 = 0; t16 < 4; ++t16)
#pragma unroll
          for (int r = 0; r < 4; ++r)
            if (kbase + t16 * 16 > qbase + r) s4[t16][r] = -1e30f;
      }
      // online softmax across 16 key-lanes
      float mx[4];
#pragma unroll
      for (int r = 0; r < 4; ++r)
        mx[r] = fmaxf(fmaxf(s4[0][r], s4[1][r]), fmaxf(s4[2][r], s4[3][r]));
#pragma unroll
      for (int off = 1; off < 16; off <<= 1)
#pragma unroll
        for (int r = 0; r < 4; ++r) mx[r] = fmaxf(mx[r], __shfl_xor(mx[r], off));
      float fac[4];
#pragma unroll
      for (int r = 0; r < 4; ++r) {
        const float mn = fmaxf(mrow[r], mx[r]);
        fac[r] = __expf(mrow[r] - mn);
        mrow[r] = mn;
      }
      float psum[4] = {0.f, 0.f, 0.f, 0.f};
#pragma unroll
      for (int t16 = 0; t16 < 4; ++t16)
#pragma unroll
        for (int r = 0; r < 4; ++r) {
          const float pv = __expf(s4[t16][r] - mrow[r]);
          psum[r] += pv;
          Ps[w][g * 4 + r][t16 * 16 + c] = f2bf(pv);
        }
#pragma unroll
      for (int off = 1; off < 16; off <<= 1)
#pragma unroll
        for (int r = 0; r < 4; ++r) psum[r] += __shfl_xor(psum[r], off);
#pragma unroll
      for (int r = 0; r < 4; ++r) lrow[r] = lrow[r] * fac[r] + psum[r];
#pragma unroll
      for (int d = 0; d < 4; ++d)
#pragma unroll
        for (int r = 0; r < 4; ++r) o[d][r] *= fac[r];
      // O += P V
#pragma unroll
      for (int ks = 0; ks < 2; ++ks) {
        const bf16x8 pf = *(const bf16x8*)&Ps[w][c][ks * 32 + g * 8];
#pragma unroll
        for (int d = 0; d < 4; ++d) {
          const bf16x8 vf = *(const bf16x8*)&Vs[d * 16 + c][ks * 32 + g * 8];
          o[d] = mfma16(pf, vf, o[d]);
        }
      }
    }
#pragma unroll
    for (int d = 0; d < 4; ++d)
#pragma unroll
      for (int r = 0; r < 4; ++r) {
        const float v = o[d][r] / lrow[r];
        ctx[(size_t)(b * 2048 + q0 + w * 16 + g * 4 + r) * 1024 + h * 64 + d * 16 + c] = f2bf(v);
      }
  }
}

// ---------------- launch ----------------

extern "C" void kernel_launch(void* const* d_in, const int* in_sizes, int n_in,
                              void* d_out, int out_size, void* d_ws, size_t ws_size,
                              hipStream_t stream) {
  const float* hidden = (const float*)d_in[0];
  const float* ln1g = (const float*)d_in[1];
  const float* ln1b = (const float*)d_in[2];
  const float* ln2g = (const float*)d_in[3];
  const float* ln2b = (const float*)d_in[4];
  const float* qU = (const float*)d_in[5];
  const float* qV = (const float*)d_in[6];
  const float* qb = (const float*)d_in[7];
  const float* kU = (const float*)d_in[8];
  const float* kV = (const float*)d_in[9];
  const float* kb = (const float*)d_in[10];
  const float* vU = (const float*)d_in[11];
  const float* vV = (const float*)d_in[12];
  const float* vb = (const float*)d_in[13];
  const float* outU = (const float*)d_in[14];
  const float* outV = (const float*)d_in[15];
  const float* outb = (const float*)d_in[16];
  const float* fc1U = (const float*)d_in[17];
  const float* fc1V = (const float*)d_in[18];
  const float* fc1b = (const float*)d_in[19];
  const float* fc2U = (const float*)d_in[20];
  const float* fc2V = (const float*)d_in[21];
  const float* fc2b = (const float*)d_in[22];
  float* out = (float*)d_out;

  // workspace carve, lifetime-based aliasing
  char* p = (char*)d_ws;
  unsigned short* x1x2 = (unsigned short*)p; p += (size_t)4096 * 1024 * 2;   // x1 (LN1), later x2 (LN2)
  unsigned short* WqT_t1 = (unsigned short*)p; p += (size_t)3072 * 1024 * 2; // Wqkv^T, later t1
  float* bqkv = (float*)p; p += 3072 * 4;
  char* bigA = p; p += (size_t)4096 * 3072 * 2 + (size_t)4096 * 1024 * 2;    // QKV + ctx, later hmid
  unsigned short* QKV = (unsigned short*)bigA;
  unsigned short* ctxb = (unsigned short*)(bigA + (size_t)4096 * 3072 * 2);
  unsigned short* hmid = (unsigned short*)bigA;
  char* wo = p; p += (size_t)1024 * 768 * 2 * 2 + (size_t)1024 * 1024 * 2;   // outU,outV^T,Wout^T, later t2
  unsigned short* outUb = (unsigned short*)wo;
  unsigned short* outVT = (unsigned short*)(wo + (size_t)1024 * 768 * 2);
  unsigned short* WoutT = (unsigned short*)(wo + (size_t)1024 * 768 * 2 * 2);
  unsigned short* t2 = (unsigned short*)wo;
  float* hbuf = (float*)p; p += (size_t)4096 * 1024 * 4;                     // h (fp32 residual); VT aliases pre-attn
  unsigned short* VT = (unsigned short*)hbuf;                                // [32][64][2048] bf16 = 8MB
  unsigned short* fc1UT = (unsigned short*)p; p += (size_t)512 * 1024 * 2;
  unsigned short* fc1VT = (unsigned short*)p; p += (size_t)4096 * 512 * 2;
  unsigned short* fc2UT = (unsigned short*)p; p += (size_t)512 * 4096 * 2;
  unsigned short* fc2VT = (unsigned short*)p; p += (size_t)1024 * 512 * 2;

  const dim3 b256(256);
  const dim3 tb(32, 8);

  // weight prep
  concat_bias_k<<<12, b256, 0, stream>>>(qb, kb, vb, bqkv);
  wqkv_pre_k<<<dim3(16, 48), b256, 0, stream>>>(qU, qV, kU, kV, vU, vV, WqT_t1);
  tcvt_k<<<dim3(32, 24), tb, 0, stream>>>(outV, outVT, 768, 1024);
  cvt_k<<<768, b256, 0, stream>>>(outU, outUb, 1024 * 768);
  tcvt_k<<<dim3(16, 32), tb, 0, stream>>>(fc1U, fc1UT, 1024, 512);
  tcvt_k<<<dim3(128, 16), tb, 0, stream>>>(fc1V, fc1VT, 512, 4096);
  tcvt_k<<<dim3(16, 128), tb, 0, stream>>>(fc2U, fc2UT, 4096, 512);
  tcvt_k<<<dim3(32, 16), tb, 0, stream>>>(fc2V, fc2VT, 512, 1024);

  // attention path
  ln_k<<<4096, b256, 0, stream>>>(hidden, ln1g, ln1b, x1x2);
  gemm_k<128, 1, 1><<<dim3(24, 32), b256, 0, stream>>>(x1x2, WqT_t1, bqkv, nullptr, QKV, 4096, 3072, 1024);
  vtr_k<<<dim3(64, 2, 32), tb, 0, stream>>>(QKV, VT);
  gemm_k<128, 0, 1><<<dim3(8, 8), b256, 0, stream>>>(outVT, outUb, nullptr, nullptr, WoutT, 1024, 1024, 768);
  attn_k<<<dim3(16, 32), b256, 0, stream>>>(QKV, VT, ctxb);
  gemm_k<128, 3, 0><<<dim3(8, 32), b256, 0, stream>>>(ctxb, WoutT, outb, hidden, hbuf, 4096, 1024, 1024);

  // MLP path
  ln_k<<<4096, b256, 0, stream>>>(hbuf, ln2g, ln2b, x1x2);
  gemm_k<64, 0, 1><<<dim3(8, 32), b256, 0, stream>>>(x1x2, fc1UT, nullptr, nullptr, WqT_t1, 4096, 512, 1024);
  gemm_k<128, 2, 1><<<dim3(32, 32), b256, 0, stream>>>(WqT_t1, fc1VT, fc1b, nullptr, hmid, 4096, 4096, 512);
  gemm_k<64, 0, 1><<<dim3(8, 32), b256, 0, stream>>>(hmid, fc2UT, nullptr, nullptr, t2, 4096, 512, 4096);
  gemm_k<128, 3, 0><<<dim3(8, 32), b256, 0, stream>>>(t2, fc2VT, fc2b, hbuf, out, 4096, 1024, 512);
}